// Round 4
// baseline (86.862 us; speedup 1.0000x reference)
//
#include <hip/hip_runtime.h>

#define NCH 24
#define KS 11
#define TH 32          // output rows per tile
#define TW 32          // output cols per tile
#define IWC 44         // LDS col stride (TW+10, padded to mult of 4)
#define NRG 6          // row groups in vertical pass
#define RPG 6          // v-rows per group (covers 36, top 4 masked)

typedef float vbuf_t[TH][IWC];   // one field: 32 x 44

// ================= core tile: vertical-first sep-conv + SSIM ==============
template<bool GUARD>
__device__ __forceinline__ void ssim_tile(
    const float* __restrict__ Xp, const float* __restrict__ Yp,
    const float* __restrict__ k, int H, int W, int gx0, int gy0, int tid,
    vbuf_t* vbuf, float& ss_acc, float& cs_acc)
{
    // ---- vertical pass: 6 row-groups x 42 cols = 252 threads, 6 v-rows each
    if (tid < NRG * 42) {
        const int c  = tid % 42;
        const int rg = tid / 42;
        const int r0 = rg * RPG;             // v-rows r0..r0+5 (rows >=32 masked)
        const int gc = gx0 + c;
        const bool cok = (!GUARD) || (gc < W);

        float acc[RPG][5];
#pragma unroll
        for (int i = 0; i < RPG; ++i)
#pragma unroll
            for (int f = 0; f < 5; ++f) acc[i][f] = 0.f;

        const float* xptr = Xp + (size_t)(gy0 + r0) * W + gc;
        const float* yptr = Yp + (size_t)(gy0 + r0) * W + gc;

#pragma unroll
        for (int ri = 0; ri < RPG + 10; ++ri) {       // 16 input rows
            float xv, yv;
            if (GUARD) {
                const int gy = gy0 + r0 + ri;
                xv = 0.f; yv = 0.f;
                if (cok && gy < H) { xv = xptr[0]; yv = yptr[0]; }
            } else {
                xv = xptr[0]; yv = yptr[0];
            }
            xptr += W; yptr += W;
            const float xx = xv * xv, yy = yv * yv, xy = xv * yv;
#pragma unroll
            for (int rv = 0; rv < RPG; ++rv) {
                if (rv < (ri > 10 ? ri - 10 : 0)) continue;   // compile-time folded
                if (rv > (ri < RPG - 1 ? ri : RPG - 1)) continue;
                const float kt = k[ri - rv];
                acc[rv][0] += kt * xv;
                acc[rv][1] += kt * yv;
                acc[rv][2] += kt * xx;
                acc[rv][3] += kt * yy;
                acc[rv][4] += kt * xy;
            }
        }
#pragma unroll
        for (int rv = 0; rv < RPG; ++rv) {
            const int r = r0 + rv;
            if (r < TH) {
#pragma unroll
                for (int f = 0; f < 5; ++f)
                    vbuf[f][r][c] = acc[rv][f];
            }
        }
    }
    __syncthreads();

    // ---- horizontal pass: b128 LDS reads + SSIM (c0=4*cg -> 8-phase minimum)
    const float c1 = 1e-4f, c2 = 9e-4f;
    const int row = tid >> 3;          // 0..31
    const int cg  = tid & 7;           // 0..7
    const int c0  = cg * 4;
    const bool rowok = (!GUARD) || ((gy0 + row) <= (H - KS));

    float hacc[5][4];
#pragma unroll
    for (int f = 0; f < 5; ++f)
#pragma unroll
        for (int j = 0; j < 4; ++j) hacc[f][j] = 0.f;

#pragma unroll
    for (int f = 0; f < 5; ++f) {
        const float4* vp = reinterpret_cast<const float4*>(&vbuf[f][row][c0]);
        float4 q0 = vp[0], q1 = vp[1], q2 = vp[2], q3 = vp[3];
        float v[16] = {q0.x,q0.y,q0.z,q0.w, q1.x,q1.y,q1.z,q1.w,
                       q2.x,q2.y,q2.z,q2.w, q3.x,q3.y,q3.z,q3.w};
#pragma unroll
        for (int j = 0; j < 4; ++j)
#pragma unroll
            for (int t = 0; t < KS; ++t)
                hacc[f][j] += k[t] * v[j + t];
    }

#pragma unroll
    for (int j = 0; j < 4; ++j) {
        bool ok = rowok && ((!GUARD) || ((gx0 + c0 + j) <= (W - KS)));
        if (ok) {
            float mx = hacc[0][j], my = hacc[1][j];
            float vxx = hacc[2][j], vyy = hacc[3][j], vxy = hacc[4][j];
            float mxx = mx * mx, myy = my * my, mxy = mx * my;
            float sxx = vxx - mxx, syy = vyy - myy, sxy = vxy - mxy;
            float cs = (2.f * sxy + c2) * __builtin_amdgcn_rcpf(sxx + syy + c2);
            float ssv = (2.f * mxy + c1) * __builtin_amdgcn_rcpf(mxx + myy + c1) * cs;
            ss_acc += ssv; cs_acc += cs;
        }
    }
}

__device__ __forceinline__ void block_reduce_store(
    float ss_acc, float cs_acc, int tid, float* red, float* slot)
{
    for (int off = 32; off > 0; off >>= 1) {
        ss_acc += __shfl_down(ss_acc, off);
        cs_acc += __shfl_down(cs_acc, off);
    }
    const int wave = tid >> 6;
    if ((tid & 63) == 0) { red[wave * 2] = ss_acc; red[wave * 2 + 1] = cs_acc; }
    __syncthreads();
    if (tid == 0) {
        slot[0] = red[0] + red[2] + red[4] + red[6];
        slot[1] = red[1] + red[3] + red[5] + red[7];
    }
}

// ================= scale-0: SSIM + full pooled-pyramid epilogue ===========
__global__ __launch_bounds__(256, 5) void ssim_scale0_kernel(
    const float* __restrict__ X, const float* __restrict__ Y,
    const float* __restrict__ kern, float* __restrict__ part,
    float* __restrict__ X1, float* __restrict__ Y1,
    float* __restrict__ X2, float* __restrict__ Y2,
    float* __restrict__ X3, float* __restrict__ Y3,
    float* __restrict__ X4, float* __restrict__ Y4)
{
    const int H = 512, W = 512;
    const int nc  = blockIdx.z;
    const int ch  = nc % 3;
    const int gx0 = blockIdx.x * TW;
    const int gy0 = blockIdx.y * TH;
    const int tid = threadIdx.x;

    __shared__ __align__(16) float vbuf[5][TH][IWC];
    __shared__ float red[8];

    float k[KS];
#pragma unroll
    for (int t = 0; t < KS; ++t) k[t] = kern[ch * KS + t];

    const float* Xp = X + (size_t)nc * H * W;
    const float* Yp = Y + (size_t)nc * H * W;

    float ss_acc = 0.f, cs_acc = 0.f;
    const bool guard = (gx0 + IWC > W) || (gy0 + TH + 10 > H);
    if (guard) ssim_tile<true >(Xp, Yp, k, H, W, gx0, gy0, tid, (vbuf_t*)vbuf, ss_acc, cs_acc);
    else       ssim_tile<false>(Xp, Yp, k, H, W, gx0, gy0, tid, (vbuf_t*)vbuf, ss_acc, cs_acc);
    __syncthreads();   // vbuf reads done -> reuse as pyramid scratch

    // ---- pooled pyramid: 32x32 tile -> 16x16 -> 8x8 -> 4x4 -> 2x2 per array
    float* pb = (float*)vbuf;
    {
        const int W2 = W >> 1;
        for (int p = tid; p < 512; p += 256) {         // level 1: 2 arrays x 256
            int a = p >> 8, q = p & 255;
            int pr = q >> 4, pc = q & 15;
            int sr = gy0 + 2 * pr, sc = gx0 + 2 * pc;
            const float* sp = (a ? Yp : Xp) + (size_t)sr * W + sc;
            float v = 0.25f * (sp[0] + sp[1] + sp[W] + sp[W + 1]);
            pb[a * 256 + q] = v;
            size_t di = (size_t)nc * W2 * W2 + (size_t)((gy0 >> 1) + pr) * W2 + ((gx0 >> 1) + pc);
            (a ? Y1 : X1)[di] = v;
        }
    }
    __syncthreads();
    if (tid < 128) {                                    // level 2: 2 arrays x 64
        const int W4 = W >> 2;
        int a = tid >> 6, q = tid & 63;
        int pr = q >> 3, pc = q & 7;
        const float* src = pb + a * 256;
        float v = 0.25f * (src[(2*pr)*16 + 2*pc] + src[(2*pr)*16 + 2*pc + 1] +
                           src[(2*pr+1)*16 + 2*pc] + src[(2*pr+1)*16 + 2*pc + 1]);
        pb[512 + a * 64 + q] = v;
        size_t di = (size_t)nc * W4 * W4 + (size_t)((gy0 >> 2) + pr) * W4 + ((gx0 >> 2) + pc);
        (a ? Y2 : X2)[di] = v;
    }
    __syncthreads();
    if (tid < 32) {                                     // level 3: 2 arrays x 16
        const int W8 = W >> 3;
        int a = tid >> 4, q = tid & 15;
        int pr = q >> 2, pc = q & 3;
        const float* src = pb + 512 + a * 64;
        float v = 0.25f * (src[(2*pr)*8 + 2*pc] + src[(2*pr)*8 + 2*pc + 1] +
                           src[(2*pr+1)*8 + 2*pc] + src[(2*pr+1)*8 + 2*pc + 1]);
        pb[640 + a * 16 + q] = v;
        size_t di = (size_t)nc * W8 * W8 + (size_t)((gy0 >> 3) + pr) * W8 + ((gx0 >> 3) + pc);
        (a ? Y3 : X3)[di] = v;
    }
    __syncthreads();
    if (tid < 8) {                                      // level 4: 2 arrays x 4
        const int W16 = W >> 4;
        int a = tid >> 2, q = tid & 3;
        int pr = q >> 1, pc = q & 1;
        const float* src = pb + 640 + a * 16;
        float v = 0.25f * (src[(2*pr)*4 + 2*pc] + src[(2*pr)*4 + 2*pc + 1] +
                           src[(2*pr+1)*4 + 2*pc] + src[(2*pr+1)*4 + 2*pc + 1]);
        size_t di = (size_t)nc * W16 * W16 + (size_t)((gy0 >> 4) + pr) * W16 + ((gx0 >> 4) + pc);
        (a ? Y4 : X4)[di] = v;
    }

    int t = blockIdx.y * gridDim.x + blockIdx.x;
    block_reduce_store(ss_acc, cs_acc, tid, red,
                       part + ((size_t)nc * (gridDim.x * gridDim.y) + t) * 2);
}

// ================= merged scales 1-4 ======================================
__global__ __launch_bounds__(256, 5) void ssim_rest_kernel(
    const float* __restrict__ x1, const float* __restrict__ y1,
    const float* __restrict__ x2, const float* __restrict__ y2,
    const float* __restrict__ x3, const float* __restrict__ y3,
    const float* __restrict__ x4, const float* __restrict__ y4,
    const float* __restrict__ kern, float* __restrict__ part)
{
    const int z = blockIdx.z;
    const int tid = threadIdx.x;

    int img, bx, by, H, poff, nt, gw;
    const float *Xs, *Ys;
    if (z < 1536)      { int r = z;        img = r >> 6; int t = r & 63; bx = t & 7; by = t >> 3; H = 256; Xs = x1; Ys = y1; poff = 12288; nt = 64; gw = 8; }
    else if (z < 1920) { int r = z - 1536; img = r >> 4; int t = r & 15; bx = t & 3; by = t >> 2; H = 128; Xs = x2; Ys = y2; poff = 15360; nt = 16; gw = 4; }
    else if (z < 2016) { int r = z - 1920; img = r >> 2; int t = r & 3;  bx = t & 1; by = t >> 1; H = 64;  Xs = x3; Ys = y3; poff = 16128; nt = 4;  gw = 2; }
    else               { img = z - 2016;   bx = 0; by = 0;                           H = 32;  Xs = x4; Ys = y4; poff = 16320; nt = 1;  gw = 1; }
    const int W = H;
    const int gx0 = bx * TW, gy0 = by * TH;
    const int ch = img % 3;

    __shared__ __align__(16) float vbuf[5][TH][IWC];
    __shared__ float red[8];

    float k[KS];
#pragma unroll
    for (int t = 0; t < KS; ++t) k[t] = kern[ch * KS + t];

    const float* Xp = Xs + (size_t)img * H * W;
    const float* Yp = Ys + (size_t)img * H * W;

    float ss_acc = 0.f, cs_acc = 0.f;
    const bool guard = (gx0 + IWC > W) || (gy0 + TH + 10 > H);
    if (guard) ssim_tile<true >(Xp, Yp, k, H, W, gx0, gy0, tid, (vbuf_t*)vbuf, ss_acc, cs_acc);
    else       ssim_tile<false>(Xp, Yp, k, H, W, gx0, gy0, tid, (vbuf_t*)vbuf, ss_acc, cs_acc);

    int tl = by * gw + bx;
    block_reduce_store(ss_acc, cs_acc, tid, red,
                       part + poff + ((size_t)img * nt + tl) * 2);
}

// ================= finalize ==============================================
__global__ __launch_bounds__(256) void finalize_kernel(
    const float* __restrict__ part, const float* __restrict__ wts,
    float* __restrict__ out)
{
    __shared__ float smean[NCH][5];
    __shared__ float prods[NCH];
    const int ntiles[5] = {256, 64, 16, 4, 1};
    const int bases[5]  = {0, 12288, 15360, 16128, 16320};
    const float counts[5] = {252004.f, 60516.f, 13924.f, 2916.f, 484.f};
    int tid = threadIdx.x;

    for (int p = tid; p < NCH * 5; p += blockDim.x) {
        int s = p % 5, nc = p / 5;
        int nt = ntiles[s];
        const float* base = part + bases[s] + (size_t)nc * nt * 2;
        int sel = (s == 4) ? 0 : 1;   // ss for last scale, cs otherwise
        float acc = 0.f;
        for (int t = 0; t < nt; ++t) acc += base[t * 2 + sel];
        smean[nc][s] = acc / counts[s];
    }
    __syncthreads();
    if (tid < NCH) {
        float pr = 1.f;
#pragma unroll
        for (int s = 0; s < 5; ++s) {
            float v = fmaxf(smean[tid][s], 0.f);
            pr *= powf(v, wts[s]);
        }
        prods[tid] = pr;
    }
    __syncthreads();
    if (tid == 0) {
        float m = 0.f;
        for (int i = 0; i < NCH; ++i) m += prods[i];
        out[0] = m / (float)NCH;
    }
}

extern "C" void kernel_launch(void* const* d_in, const int* in_sizes, int n_in,
                              void* d_out, int out_size, void* d_ws, size_t ws_size,
                              hipStream_t stream)
{
    const float* x    = (const float*)d_in[0];
    const float* y    = (const float*)d_in[1];
    const float* kern = (const float*)d_in[2];
    const float* wts  = (const float*)d_in[3];
    float* out = (float*)d_out;
    float* ws  = (float*)d_ws;

    size_t o = 0;
    float* x1 = ws + o; o += (size_t)NCH * 256 * 256;
    float* y1 = ws + o; o += (size_t)NCH * 256 * 256;
    float* x2 = ws + o; o += (size_t)NCH * 128 * 128;
    float* y2 = ws + o; o += (size_t)NCH * 128 * 128;
    float* x3 = ws + o; o += (size_t)NCH * 64 * 64;
    float* y3 = ws + o; o += (size_t)NCH * 64 * 64;
    float* x4 = ws + o; o += (size_t)NCH * 32 * 32;
    float* y4 = ws + o; o += (size_t)NCH * 32 * 32;
    float* part = ws + o;  // 16368 floats

    ssim_scale0_kernel<<<dim3(16, 16, NCH), 256, 0, stream>>>(
        x, y, kern, part, x1, y1, x2, y2, x3, y3, x4, y4);

    ssim_rest_kernel<<<dim3(1, 1, 2040), 256, 0, stream>>>(
        x1, y1, x2, y2, x3, y3, x4, y4, kern, part);

    finalize_kernel<<<1, 256, 0, stream>>>(part, wts, out);
}